// Round 18
// baseline (187.247 us; speedup 1.0000x reference)
//
#include <hip/hip_runtime.h>
#include <hip/hip_bf16.h>
#include <string.h>

#define D_ 256
#define K_ 1024
#define T_ 2048
#define B_ 32
#define N_ 65536   // B*T

// out element offsets (f32 elements, outputs concatenated in return order)
#define OFF_ZQ   0u
#define OFF_IDS  16777216u
#define OFF_LOSS 16842752u
#define OFF_EMB  16842753u
#define OFF_CNT  17104897u
#define OFF_W    17105921u

// ---- ws layout ----
#define WS_IDS     0x000000u   // int[65536]
#define WS_ZN      0x040000u   // float[65536]
#define WS_ORDER   0x080000u   // int[65536]  packed (id<<16)|token
#define WS_SUMS    0x0C0000u   // float[262144] (1 MB)
#define WS_COUNTS  0x1C0000u   // float[1024]
#define WS_EN      0x1C1000u   // float[1024]
#define WS_SM      0x1C2000u   // float[1024] (fallback only)
#define WS_OFFS    0x1C3000u   // int[1024]
#define WS_CURSOR  0x1C4000u   // int[1024]
#define WS_LOSS    0x1C5000u   // double[1]
#define WS_END_SM  0x1C6000u
// fp16 path regions
#define WS_ESPLIT  0x290000u   // fp16[1024*256] (512 KB), e scaled by 256
#define WS_ZSPLIT  0x1000000u  // fp16[65536*256] (32 MB)
#define WS_END_XL  0x3000000u

#define TAU 2.0e-4f

typedef float f32x4 __attribute__((ext_vector_type(4)));
typedef _Float16 f16x8 __attribute__((ext_vector_type(8)));
typedef unsigned short ushort_t;
typedef unsigned long long u64;

static __device__ inline float fmul_rn_opaque(float a, float b) {
  float r = a * b;
  asm volatile("" : "+v"(r));
  return r;
}

static __device__ inline ushort_t f2h(float x) {   // f32 -> fp16 RNE bits
  _Float16 h = (_Float16)x;
  ushort_t u;
  __builtin_memcpy(&u, &h, 2);
  return u;
}
static __device__ inline float h2f(ushort_t u) {
  _Float16 h;
  __builtin_memcpy(&h, &u, 2);
  return (float)h;
}

static __device__ inline u64 skey(float s, int j) {
  unsigned int u = __float_as_uint(s);
  u = u ^ ((unsigned int)((int)u >> 31) | 0x80000000u);
  return ((u64)u << 32) | (unsigned int)j;
}
static __device__ inline float key_s(u64 k) {
  unsigned int u = (unsigned int)(k >> 32);
  u = (u & 0x80000000u) ? (u ^ 0x80000000u) : ~u;
  return __uint_as_float(u);
}

// async global->LDS, 16B per lane (lds dest = wave-uniform base + lane*16)
static __device__ __forceinline__ void gload16(const void* g, void* l) {
  __builtin_amdgcn_global_load_lds(
      (const __attribute__((address_space(1))) void*)g,
      (__attribute__((address_space(3))) void*)l, 16, 0, 0);
}

// numpy pairwise_sum replica for n=256 (fallback kernels only)
template <typename F>
static __device__ inline float np_pairwise256(F term) {
  float h0 = 0.f, h1 = 0.f;
#pragma unroll
  for (int half = 0; half < 2; ++half) {
    const int base = half * 128;
    float r[8];
#pragma unroll
    for (int k = 0; k < 8; ++k) r[k] = term(base + k);
    for (int i = 8; i < 128; i += 8) {
#pragma unroll
      for (int k = 0; k < 8; ++k) r[k] += term(base + i + k);
    }
    float v = ((r[0] + r[1]) + (r[2] + r[3])) + ((r[4] + r[5]) + (r[6] + r[7]));
    if (half == 0) h0 = v; else h1 = v;
  }
  return h0 + h1;
}

// ---------------- fused en + esplit (fp16, e*256), 8 lanes per code --------
__global__ __launch_bounds__(256) void k_eprep(const float* __restrict__ emb,
                                               float* __restrict__ en,
                                               ushort_t* __restrict__ esplit) {
  const int tid = threadIdx.x;
  const int j = blockIdx.x * 32 + (tid >> 3);   // code
  const int k = tid & 7;
  const float* e = emb + (size_t)j * D_;

  float h[2];
#pragma unroll
  for (int half = 0; half < 2; ++half) {
    float r = 0.f;
    for (int i = 0; i < 16; ++i) {
      float x = e[half * 128 + 8 * i + k];
      float t = fmul_rn_opaque(x, x);
      r = (i == 0) ? t : r + t;
    }
    float s = r + __shfl_xor(r, 1, 64);
    s = s + __shfl_xor(s, 2, 64);
    s = s + __shfl_xor(s, 4, 64);
    h[half] = s;
  }
  if (k == 0) en[j] = h[0] + h[1];

  ushort_t* er = esplit + (size_t)j * 256;
#pragma unroll
  for (int m = 0; m < 32; m += 4) {
    float4 v = *reinterpret_cast<const float4*>(e + k * 32 + m);
    *reinterpret_cast<ushort4*>(er + k * 32 + m) =
        make_ushort4(f2h(v.x * 256.f), f2h(v.y * 256.f),
                     f2h(v.z * 256.f), f2h(v.w * 256.f));
  }
}

// ---------------- fused zn (np-exact, lane-parallel) + zsplit (fp16) -------
__global__ __launch_bounds__(256) void k_zprep(const float* __restrict__ z,
                                               float* __restrict__ zn,
                                               ushort_t* __restrict__ zsplit) {
  __shared__ float tile[64][68];
  const int tid = threadIdx.x, bid = blockIdx.x;
  const int tchunk = bid & 31, b = bid >> 5;
  const int n0 = b * T_ + tchunk * 64;
  const int t4 = tid & 15, rq = tid >> 4;
  const int tok = tid >> 2, p = tid & 3;

  float r0 = 0.f, r1 = 0.f, h0 = 0.f;
  for (int c = 0; c < 4; ++c) {
    __syncthreads();
    const float* zp = z + (size_t)b * D_ * T_ + (size_t)(c * 64) * T_ + tchunk * 64;
#pragma unroll
    for (int i = 0; i < 4; ++i) {
      int dd = rq + 16 * i;
      *reinterpret_cast<float4*>(&tile[dd][t4 * 4]) =
          *reinterpret_cast<const float4*>(&zp[(size_t)dd * T_ + t4 * 4]);
    }
    __syncthreads();
    {
      ushort_t* dst = zsplit + (size_t)(n0 + tok) * 256 + c * 64 + p * 16;
      unsigned int wbuf[8];
#pragma unroll
      for (int jj = 0; jj < 16; jj += 2) {
        float x0 = tile[p * 16 + jj][tok];
        float x1 = tile[p * 16 + jj + 1][tok];
        wbuf[jj >> 1] = (unsigned int)f2h(x0) | ((unsigned int)f2h(x1) << 16);
      }
      *reinterpret_cast<uint4*>(dst) = make_uint4(wbuf[0], wbuf[1], wbuf[2], wbuf[3]);
      *reinterpret_cast<uint4*>(dst + 8) = make_uint4(wbuf[4], wbuf[5], wbuf[6], wbuf[7]);
    }
#pragma unroll
    for (int il = 0; il < 8; ++il) {
      float x0 = tile[8 * il + 2 * p][tok];
      float x1 = tile[8 * il + 2 * p + 1][tok];
      float t0 = fmul_rn_opaque(x0, x0);
      float t1 = fmul_rn_opaque(x1, x1);
      if ((c & 1) == 0 && il == 0) { r0 = t0; r1 = t1; }
      else { r0 += t0; r1 += t1; }
    }
    if (c & 1) {
      float s = r0 + r1;
      s = s + __shfl_xor(s, 1, 64);
      s = s + __shfl_xor(s, 2, 64);
      if (c == 1) h0 = s;
      else if (p == 0) zn[n0 + tok] = h0 + s;
    }
  }
}

// ---------------- top-2 merge helper ----------------
static __device__ inline void top2merge(u64& k1, u64& k2, u64 o1, u64 o2) {
  if (o1 < k1) { u64 t = k1 < o2 ? k1 : o2; k2 = t; k1 = o1; }
  else { k2 = k2 < o1 ? k2 : o1; }
}

// ---------------- FUSED: GEMM + screen + rescreen + ids/loss + z_q --------
// One block per 256-token tile; loops all 4 code-tiles internally. Per
// (ct,wm) top-2 -> 16 candidate keys/token in ldsK (superset of r17's 8).
// Inline TAU screen + np-faithful rescreen + key-derived loss, then
// gather/transpose z_q write for the tile (ids known locally).
__global__ __launch_bounds__(512) void k_gemm(
    const ushort_t* __restrict__ zsplit, const ushort_t* __restrict__ esplit,
    const float* __restrict__ en, const float* __restrict__ zn,
    const float* __restrict__ z, const float* __restrict__ emb,
    int* __restrict__ ids, float* __restrict__ counts,
    double* __restrict__ loss, float* __restrict__ out) {
  __shared__ char ldsbuf[65536];   // [Z 32K | E 32K] staging; later z_q tiles
  __shared__ u64 ldsK[256][16];    // 32 KB candidate keys
  __shared__ int idsl[256];
  __shared__ float ls[8];

  const int tid = threadIdx.x;
  const int w = blockIdx.x;                  // 256 blocks
  const int xcd = w & 7;
  const int tt = (xcd << 5) + (w >> 3);      // token tile 0..255 (XCD map)
  const int r0 = tt * 256;

  const int lane = tid & 63;
  const int wv = tid >> 6;               // wave 0..7
  const int wm = wv >> 2, wn = wv & 3;   // wm: code half, wn: token quarter
  const int m16 = lane & 15;
  const int g = lane >> 4;
  const int gb = g << 4;

  const int rl = lane >> 3;
  const int vlane = rl * 512 + ((((lane & 7) << 4)) ^ (rl << 4));
  const char* gza = (const char*)zsplit + (size_t)(r0 + wv * 32) * 512 + vlane;
  const char* geabase = (const char*)esplit + (size_t)(wv * 32) * 512 + vlane;

  const char* Zb = ldsbuf;
  const char* Eb = ldsbuf + 32768;

  for (int ct = 0; ct < 4; ++ct) {
    const int c0 = ct * 256;
    const char* gea = geabase + (size_t)c0 * 512;

    f32x4 acc[8][4];
#pragma unroll
    for (int mi = 0; mi < 8; ++mi)
#pragma unroll
      for (int ni = 0; ni < 4; ++ni) acc[mi][ni] = f32x4{0.f, 0.f, 0.f, 0.f};

    auto STAGE = [&](int it_) {
      const int kb = it_ << 7;
      char* lz = ldsbuf + wv * 4096;
      char* le = ldsbuf + 32768 + wv * 4096;
#pragma unroll
      for (int i = 0; i < 4; ++i) {
        gload16(gza + kb + i * 4096, lz + i * 1024);
        gload16(gea + kb + i * 4096, le + i * 1024);
      }
    };

    STAGE(0);
    __builtin_amdgcn_sched_barrier(0);

    for (int it = 0; it < 4; ++it) {
      asm volatile("s_waitcnt vmcnt(0)" ::: "memory");
      __builtin_amdgcn_sched_barrier(0);
      __builtin_amdgcn_s_barrier();
      __builtin_amdgcn_sched_barrier(0);

#pragma unroll
      for (int ks = 0; ks < 2; ++ks) {
        f16x8 ef[8], zf[4];
#pragma unroll
        for (int mi = 0; mi < 8; ++mi) {     // A-operand: codes
          int row = wm * 128 + mi * 16 + m16;
          ef[mi] = *reinterpret_cast<const f16x8*>(
              Eb + row * 128 + (((ks << 6) + gb) ^ ((row & 7) << 4)));
        }
#pragma unroll
        for (int ni = 0; ni < 4; ++ni) {     // B-operand: tokens
          int row = wn * 64 + ni * 16 + m16;
          zf[ni] = *reinterpret_cast<const f16x8*>(
              Zb + row * 128 + (((ks << 6) + gb) ^ ((row & 7) << 4)));
        }
#pragma unroll
        for (int mi = 0; mi < 8; ++mi)
#pragma unroll
          for (int ni = 0; ni < 4; ++ni)
            acc[mi][ni] = __builtin_amdgcn_mfma_f32_16x16x32_f16(
                ef[mi], zf[ni], acc[mi][ni], 0, 0, 0);
      }
      asm volatile("s_waitcnt lgkmcnt(0)" ::: "memory");
      __builtin_amdgcn_sched_barrier(0);
      __builtin_amdgcn_s_barrier();
      __builtin_amdgcn_sched_barrier(0);
      if (it < 3) STAGE(it + 1);
      __builtin_amdgcn_sched_barrier(0);
    }

    // per-ct epilogue: lane-local top-2 over 32 codes, 2 shuffle merges (g),
    // g==0 writes per-(ct,wm) top-2 into ldsK (no staging conflict).
    float env[8][4];
#pragma unroll
    for (int mi = 0; mi < 8; ++mi)
#pragma unroll
      for (int rg = 0; rg < 4; ++rg)
        env[mi][rg] = en[c0 + wm * 128 + mi * 16 + g * 4 + rg];

#pragma unroll
    for (int ni = 0; ni < 4; ++ni) {
      const int tok = wn * 64 + ni * 16 + m16;
      u64 k1 = ~0ull, k2 = ~0ull;
#pragma unroll
      for (int mi = 0; mi < 8; ++mi) {
#pragma unroll
        for (int rg = 0; rg < 4; ++rg) {
          int j = c0 + wm * 128 + mi * 16 + g * 4 + rg;
          float s = env[mi][rg] - acc[mi][ni][rg] * 0.0078125f;  // exact scale
          u64 key = skey(s, j);
          if (key < k1) { k2 = k1; k1 = key; }
          else if (key < k2) { k2 = key; }
        }
      }
      u64 o1 = (u64)__shfl_xor((long long)k1, 16, 64);
      u64 o2 = (u64)__shfl_xor((long long)k2, 16, 64);
      top2merge(k1, k2, o1, o2);
      o1 = (u64)__shfl_xor((long long)k1, 32, 64);
      o2 = (u64)__shfl_xor((long long)k2, 32, 64);
      top2merge(k1, k2, o1, o2);
      if (g == 0) {
        ldsK[tok][ct * 4 + wm * 2 + 0] = k1;
        ldsK[tok][ct * 4 + wm * 2 + 1] = k2;
      }
    }
  }
  __syncthreads();   // ldsK complete

  // ---- screen + rescreen + ids/counts/loss (tid < 256, token r0+tid) ----
  float loss_n = 0.f;
  if (tid < 256) {
    const int n = r0 + tid;
    const float znv = zn[n];
    u64 k[16];
#pragma unroll
    for (int i = 0; i < 16; ++i) k[i] = ldsK[tid][i];
    u64 mn = k[0];
#pragma unroll
    for (int i = 1; i < 16; ++i) mn = k[i] < mn ? k[i] : mn;
    float lim = key_s(mn) + TAU;
    int cnt = 0;
    int cj[4] = {0, 0, 0, 0};
#pragma unroll
    for (int i = 0; i < 16; ++i) {
      if (key_s(k[i]) <= lim) {
        if (cnt < 4) cj[cnt] = (int)(k[i] & 1023u);
        cnt++;
      }
    }
    int jf;
    if (cnt == 1) {
      jf = (int)(mn & 1023u);
      loss_n = znv + key_s(mn);   // gemm keys: s' = en - 2G
    } else {
      int b = n >> 11, t = n & 2047;
      const float* zb = z + (size_t)b * (D_ * (size_t)T_) + t;
      const float* e0 = emb + (size_t)cj[0] * D_;
      const float* e1 = emb + (size_t)cj[1] * D_;
      const float* e2 = emb + (size_t)cj[2] * D_;
      const float* e3 = emb + (size_t)cj[3] * D_;
      float a0 = 0.f, a1 = 0.f, a2 = 0.f, a3 = 0.f;
      for (int d = 0; d < D_; ++d) {   // ascending d, single acc: np-faithful
        float zv = zb[(size_t)d * T_];
        a0 = fmaf(zv, e0[d], a0);
        a1 = fmaf(zv, e1[d], a1);
        a2 = fmaf(zv, e2[d], a2);
        a3 = fmaf(zv, e3[d], a3);
      }
      float av[4] = {a0, a1, a2, a3};
      u64 best = ~0ull;
#pragma unroll
      for (int c = 0; c < 4; ++c) {
        if (c < cnt) {
          float A = znv + en[cj[c]];
          float s = A - 2.0f * av[c];
          u64 key = skey(s, cj[c]);
          best = key < best ? key : best;
        }
      }
      jf = (int)(best & 1023u);
      loss_n = key_s(best);       // rescreen keys include zn
    }
    ids[n] = jf;
    out[OFF_IDS + (unsigned)n] = (float)jf;
    idsl[tid] = jf;
    unsafeAtomicAdd(&counts[jf], 1.0f);
  }
  // loss block-reduce (waves 4..7 contribute 0)
  {
    float accl = loss_n;
#pragma unroll
    for (int o = 32; o; o >>= 1) accl += __shfl_down(accl, o);
    if ((tid & 63) == 0) ls[tid >> 6] = accl;
  }
  __syncthreads();   // idsl + ls visible; staging LDS now dead
  if (tid == 0) {
    float t = ls[0] + ls[1] + ls[2] + ls[3] + ls[4] + ls[5] + ls[6] + ls[7];
    unsafeAtomicAdd(loss, (double)t);
  }

  // ---- z_q gather/transpose-write for this tile (16 sub-tiles 64x64) ----
  const int half = tid >> 8;        // two sub-tiles in parallel
  const int ltid = tid & 255;
  float (*tile)[68] = reinterpret_cast<float(*)[68]>(ldsbuf + half * 17408);
  const int zb_ = r0 >> 11;         // batch
  const int t0_ = r0 & 2047;
  for (int st = 0; st < 8; ++st) {
    int s = st * 2 + half;          // 0..15
    int tg = s >> 2, dchunk = s & 3;
    {
      int tok = ltid >> 2, part = ltid & 3;
      int id = idsl[tg * 64 + tok] & 1023;
      const float* er = emb + (size_t)id * D_ + dchunk * 64 + part * 16;
#pragma unroll
      for (int kk = 0; kk < 4; ++kk) {
        float4 v = *reinterpret_cast<const float4*>(er + 4 * kk);
        int d = part * 16 + 4 * kk;
        tile[d + 0][tok] = v.x; tile[d + 1][tok] = v.y;
        tile[d + 2][tok] = v.z; tile[d + 3][tok] = v.w;
      }
    }
    __syncthreads();
    {
      const int t4 = ltid & 15, dq = ltid >> 4;
      const size_t zbase = (size_t)zb_ * D_ * T_ + (size_t)(dchunk * 64) * T_ +
                           (size_t)(t0_ + tg * 64);
#pragma unroll
      for (int i = 0; i < 4; ++i) {
        int dd = dq + 16 * i;
        size_t a = zbase + (size_t)dd * T_ + t4 * 4;
        *reinterpret_cast<float4*>(out + OFF_ZQ + a) =
            *reinterpret_cast<const float4*>(&tile[dd][t4 * 4]);
      }
    }
    __syncthreads();
  }
}

// ---------------- exclusive scan of counts -> offs, cursor ----------------
__global__ __launch_bounds__(1024) void k_offsets(const float* __restrict__ counts,
                                                  int* __restrict__ offs,
                                                  int* __restrict__ cursor) {
  int k = threadIdx.x;
  int c = (int)counts[k];
  __shared__ int s[1024];
  s[k] = c;
  __syncthreads();
  for (int off = 1; off < 1024; off <<= 1) {
    int v = (k >= off) ? s[k - off] : 0;
    __syncthreads();
    s[k] += v;
    __syncthreads();
  }
  int excl = s[k] - c;
  offs[k] = excl;
  cursor[k] = excl;
}

// ---------------- inverted index: order[slot] = (id<<16)|token -----------
__global__ __launch_bounds__(256) void k_bucket(const int* __restrict__ ids,
                                                int* __restrict__ cursor,
                                                int* __restrict__ order) {
  int n = blockIdx.x * 256 + threadIdx.x;
  int id = ids[n] & 1023;
  int slot = atomicAdd(&cursor[id], 1);
  order[slot & (N_ - 1)] = (id << 16) | n;
}

// ---------------- segment sums from fp16 zsplit (d-pair uint loads) -------
__global__ __launch_bounds__(256) void k_sums_bf(const ushort_t* __restrict__ zsplit,
                                                 const int* __restrict__ order,
                                                 float* __restrict__ sums) {
  __shared__ int pk[128];
  const int tid = threadIdx.x;
  if (tid < 128) pk[tid] = order[blockIdx.x * 128 + tid];
  __syncthreads();
  const int half = tid >> 7;
  const int l = tid & 127;
  const int s0 = half * 64;
  float a0 = 0.f, a1 = 0.f;
  int cur = pk[s0] >> 16;
#pragma unroll 4
  for (int i = 0; i < 64; ++i) {
    int v = pk[s0 + i];
    int code = v >> 16;
    if (code != cur) {
      unsafeAtomicAdd(&sums[(size_t)cur * D_ + 2 * l], a0);
      unsafeAtomicAdd(&sums[(size_t)cur * D_ + 2 * l + 1], a1);
      a0 = 0.f; a1 = 0.f; cur = code;
    }
    const char* row = (const char*)zsplit + (size_t)(v & 0xFFFF) * 512;
    unsigned int hw = *reinterpret_cast<const unsigned int*>(row + 4 * l);
    a0 += h2f((ushort_t)(hw & 0xFFFF));
    a1 += h2f((ushort_t)(hw >> 16));
  }
  unsafeAtomicAdd(&sums[(size_t)cur * D_ + 2 * l], a0);
  unsafeAtomicAdd(&sums[(size_t)cur * D_ + 2 * l + 1], a1);
}

// ---------------- fused: counts/n/sm + weight + embedding + loss out ------
__global__ __launch_bounds__(256) void k_weight(
    const float* __restrict__ ema_count, const float* __restrict__ counts,
    const float* __restrict__ ema_weight, const float* __restrict__ sums,
    const double* __restrict__ loss, float* __restrict__ out) {
  const int k = blockIdx.x;
  const int tid = threadIdx.x;
  __shared__ float red[4];

  float part = 0.f;
#pragma unroll
  for (int i = 0; i < 4; ++i) {
    int idx = tid + 256 * i;
    part += 0.99f * ema_count[idx] + 0.01f * counts[idx];
  }
#pragma unroll
  for (int o = 32; o; o >>= 1) part += __shfl_down(part, o);
  if ((tid & 63) == 0) red[tid >> 6] = part;
  __syncthreads();
  float n = red[0] + red[1] + red[2] + red[3];

  float nck = 0.99f * ema_count[k] + 0.01f * counts[k];
  float smo = (nck + 1.0e-5f) / (n + 1024.0f * 1.0e-5f) * n;

  int i = k * 256 + tid;
  float w = 0.99f * ema_weight[i] + 0.01f * sums[i];
  out[OFF_W + i] = w;
  out[OFF_EMB + i] = w / smo;
  if (tid == 0) {
    out[OFF_CNT + k] = nck;
    if (k == 0) {
      double mean = loss[0] / 16777216.0;
      out[OFF_LOSS] = (float)(1.25 * mean);
    }
  }
}

// ======================= fallback kernels ========================
__global__ __launch_bounds__(256) void k_en(const float* __restrict__ emb,
                                            float* __restrict__ en) {
  int j = blockIdx.x * 256 + threadIdx.x;
  const float* e = emb + (size_t)j * D_;
  en[j] = np_pairwise256([&](int d) { float x = e[d]; return fmul_rn_opaque(x, x); });
}

__global__ __launch_bounds__(256) void k_zn(const float* __restrict__ z,
                                            float* __restrict__ zn) {
  int n = blockIdx.x * 256 + threadIdx.x;
  int b = n >> 11, t = n & 2047;
  const float* zp = z + (size_t)b * (D_ * (size_t)T_) + t;
  zn[n] = np_pairwise256([&](int d) {
    float x = zp[(size_t)d * T_];
    return fmul_rn_opaque(x, x);
  });
}

__global__ __launch_bounds__(256) void k_assign(
    const float* __restrict__ z, const float* __restrict__ emb,
    const float* __restrict__ en, const float* __restrict__ zn,
    int* __restrict__ ids, float* __restrict__ counts,
    float* __restrict__ out) {
  __shared__ float zs[16][128];
  __shared__ float es[16][128];
  const int tid = threadIdx.x;
  const int tx = tid & 31;
  const int ty = tid >> 5;
  const int r0 = blockIdx.x * 128;
  const int b  = r0 >> 11;
  const int t0 = r0 & 2047;
  const float* zb = z + (size_t)b * (D_ * (size_t)T_) + t0;
  u64 keys[16];
#pragma unroll
  for (int r = 0; r < 16; ++r) keys[r] = ~0ull;
  for (int jc = 0; jc < K_; jc += 128) {
    float acc[16][4];
#pragma unroll
    for (int r = 0; r < 16; ++r)
#pragma unroll
      for (int c = 0; c < 4; ++c) acc[r][c] = 0.f;
    for (int d0 = 0; d0 < D_; d0 += 16) {
      __syncthreads();
#pragma unroll
      for (int i = 0; i < 2; ++i) {
        int slot = tid + 256 * i;
        int dd = slot >> 5, t4 = slot & 31;
        *reinterpret_cast<float4*>(&zs[dd][t4 * 4]) =
            *reinterpret_cast<const float4*>(&zb[(size_t)(d0 + dd) * T_ + t4 * 4]);
      }
#pragma unroll
      for (int i = 0; i < 2; ++i) {
        int slot = tid + 256 * i;
        int c = slot & 127, g = slot >> 7;
        int dd0 = g * 4;
        float4 ev = *reinterpret_cast<const float4*>(
            &emb[(size_t)(jc + c) * D_ + d0 + dd0]);
        es[dd0 + 0][c] = ev.x; es[dd0 + 1][c] = ev.y;
        es[dd0 + 2][c] = ev.z; es[dd0 + 3][c] = ev.w;
      }
      __syncthreads();
#pragma unroll
      for (int dd = 0; dd < 16; ++dd) {
        float4 e4 = *reinterpret_cast<const float4*>(&es[dd][tx * 4]);
        float4 z0 = *reinterpret_cast<const float4*>(&zs[dd][ty * 16]);
        float4 z1 = *reinterpret_cast<const float4*>(&zs[dd][ty * 16 + 4]);
        float4 z2 = *reinterpret_cast<const float4*>(&zs[dd][ty * 16 + 8]);
        float4 z3 = *reinterpret_cast<const float4*>(&zs[dd][ty * 16 + 12]);
        float zr[16] = {z0.x, z0.y, z0.z, z0.w, z1.x, z1.y, z1.z, z1.w,
                        z2.x, z2.y, z2.z, z2.w, z3.x, z3.y, z3.z, z3.w};
        float ec[4] = {e4.x, e4.y, e4.z, e4.w};
#pragma unroll
        for (int r = 0; r < 16; ++r)
#pragma unroll
          for (int c = 0; c < 4; ++c) acc[r][c] += zr[r] * ec[c];
      }
    }
#pragma unroll
    for (int r = 0; r < 16; ++r) {
      float znp = zn[r0 + ty * 16 + r];
      u64 kk = keys[r];
#pragma unroll
      for (int c = 0; c < 4; ++c) {
        int j = jc + tx * 4 + c;
        float A = znp + en[j];
        float s = A - 2.0f * acc[r][c];
        u64 key = skey(s, j);
        kk = key < kk ? key : kk;
      }
      keys[r] = kk;
    }
  }
#pragma unroll
  for (int r = 0; r < 16; ++r) {
    u64 kk = keys[r];
#pragma unroll
    for (int m = 1; m < 32; m <<= 1) {
      u64 o = (u64)__shfl_xor((long long)kk, m, 32);
      kk = o < kk ? o : kk;
    }
    keys[r] = kk;
  }
  if ((tid & 31) == 0) {
#pragma unroll
    for (int r = 0; r < 16; ++r) {
      int n = r0 + ty * 16 + r;
      int jf = (int)(keys[r] & 1023u);
      ids[n] = jf;
      out[OFF_IDS + (unsigned)n] = (float)jf;
      unsafeAtomicAdd(&counts[jf], 1.0f);
    }
  }
}

__global__ __launch_bounds__(256) void k_scatter_atomic(
    const float* __restrict__ z, const float* __restrict__ emb,
    const int* __restrict__ ids, float* __restrict__ sums,
    double* __restrict__ loss, float* __restrict__ out) {
  const int tid = threadIdx.x;
  unsigned int gi = blockIdx.x * 256u + (unsigned int)tid;
  int t4 = (int)(gi & 511u);
  int bd = (int)(gi >> 9);
  int d  = bd & 255;
  int b  = bd >> 8;
  size_t base = (size_t)bd * T_ + (size_t)t4 * 4;
  const float4 zv = *reinterpret_cast<const float4*>(z + base);
  const int tb = b * T_ + t4 * 4;
  float zz[4] = {zv.x, zv.y, zv.z, zv.w};
  float e4[4];
  float acc = 0.f;
#pragma unroll
  for (int u = 0; u < 4; ++u) {
    int id = ids[tb + u] & 1023;
    float e = emb[(size_t)id * D_ + d];
    float df = zz[u] - e;
    acc += df * df;
    e4[u] = e;
    unsafeAtomicAdd(&sums[(size_t)id * D_ + d], zz[u]);
  }
  *reinterpret_cast<float4*>(out + OFF_ZQ + base) =
      make_float4(e4[0], e4[1], e4[2], e4[3]);
#pragma unroll
  for (int o = 32; o; o >>= 1) acc += __shfl_down(acc, o);
  __shared__ float ls[4];
  int lane = tid & 63, wid = tid >> 6;
  if (lane == 0) ls[wid] = acc;
  __syncthreads();
  if (tid == 0) unsafeAtomicAdd(loss, (double)(ls[0] + ls[1] + ls[2] + ls[3]));
}

__global__ __launch_bounds__(1024) void k_count_fb(
    const float* __restrict__ ema_count, const float* __restrict__ counts,
    float* __restrict__ sm, const double* __restrict__ loss,
    float* __restrict__ out) {
  int k = threadIdx.x;
  float nc = 0.99f * ema_count[k] + 0.01f * counts[k];
  __shared__ float red[1024];
  red[k] = nc;
  __syncthreads();
  for (int s = 512; s > 0; s >>= 1) {
    if (k < s) red[k] += red[k + s];
    __syncthreads();
  }
  float n = red[0];
  float smo = (nc + 1.0e-5f) / (n + 1024.0f * 1.0e-5f) * n;
  sm[k] = smo;
  out[OFF_CNT + k] = nc;
  if (k == 0) {
    double mean = loss[0] / 16777216.0;
    out[OFF_LOSS] = (float)(1.25 * mean);
  }
}

__global__ __launch_bounds__(256) void k_weight_fb(
    const float* __restrict__ ema_weight, const float* __restrict__ sums,
    const float* __restrict__ sm, float* __restrict__ out) {
  int i = blockIdx.x * 256 + threadIdx.x;
  int k = i >> 8;
  float w = 0.99f * ema_weight[i] + 0.01f * sums[i];
  out[OFF_W + i] = w;
  out[OFF_EMB + i] = w / sm[k];
}

// ============================== launcher =================================
extern "C" void kernel_launch(void* const* d_in, const int* in_sizes, int n_in,
                              void* d_out, int out_size, void* d_ws, size_t ws_size,
                              hipStream_t stream) {
  const float* z          = (const float*)d_in[0];
  const float* emb        = (const float*)d_in[1];
  const float* ema_count  = (const float*)d_in[2];
  const float* ema_weight = (const float*)d_in[3];
  float* out = (float*)d_out;
  char* ws = (char*)d_ws;
  if (ws_size < (size_t)WS_END_SM) return;

  int*    ids    = (int*)(ws + WS_IDS);
  float*  zn     = (float*)(ws + WS_ZN);
  int*    order  = (int*)(ws + WS_ORDER);
  float*  sums   = (float*)(ws + WS_SUMS);
  float*  counts = (float*)(ws + WS_COUNTS);
  float*  en     = (float*)(ws + WS_EN);
  float*  sm     = (float*)(ws + WS_SM);
  int*    offs   = (int*)(ws + WS_OFFS);
  int*    cursor = (int*)(ws + WS_CURSOR);
  double* loss   = (double*)(ws + WS_LOSS);

  hipMemsetAsync(ws + WS_SUMS, 0, WS_END_SM - WS_SUMS, stream);

  if (ws_size >= (size_t)WS_END_XL) {
    // -------- fused fp16 MFMA path --------
    ushort_t* esplit = (ushort_t*)(ws + WS_ESPLIT);
    ushort_t* zsplit = (ushort_t*)(ws + WS_ZSPLIT);

    k_eprep  <<<K_ / 32, 256, 0, stream>>>(emb, en, esplit);
    k_zprep  <<<B_ * (T_ / 64), 256, 0, stream>>>(z, zn, zsplit);
    k_gemm   <<<N_ / 256, 512, 0, stream>>>(zsplit, esplit, en, zn, z, emb,
                                            ids, counts, loss, out);
    k_offsets<<<1, 1024, 0, stream>>>(counts, offs, cursor);
    k_bucket <<<N_ / 256, 256, 0, stream>>>(ids, cursor, order);
    k_sums_bf<<<N_ / 128, 256, 0, stream>>>(zsplit, order, sums);
    k_weight <<<K_, 256, 0, stream>>>(ema_count, counts, ema_weight, sums, loss, out);
  } else {
    // -------- fallback: fp32 VALU assign + atomic scatter --------
    k_en <<<K_ / 256, 256, 0, stream>>>(emb, en);
    k_zn <<<N_ / 256, 256, 0, stream>>>(z, zn);
    k_assign<<<N_ / 128, 256, 0, stream>>>(z, emb, en, zn, ids, counts, out);
    k_scatter_atomic<<<(N_ * (D_ / 4)) / 256, 256, 0, stream>>>(z, emb, ids, sums, loss, out);
    k_count_fb <<<1, 1024, 0, stream>>>(ema_count, counts, sm, loss, out);
    k_weight_fb<<<(K_ * D_) / 256, 256, 0, stream>>>(ema_weight, sums, sm, out);
  }
}

// Round 19
// 181.378 us; speedup vs baseline: 1.0324x; 1.0324x over previous
//
#include <hip/hip_runtime.h>
#include <hip/hip_bf16.h>
#include <string.h>

#define D_ 256
#define K_ 1024
#define T_ 2048
#define B_ 32
#define N_ 65536   // B*T

// out element offsets (f32 elements, outputs concatenated in return order)
#define OFF_ZQ   0u
#define OFF_IDS  16777216u
#define OFF_LOSS 16842752u
#define OFF_EMB  16842753u
#define OFF_CNT  17104897u
#define OFF_W    17105921u

// ---- ws layout ----
#define WS_IDS     0x000000u   // int[65536]
#define WS_ZN      0x040000u   // float[65536]
#define WS_ORDER   0x080000u   // int[65536]  packed (id<<16)|token
#define WS_SUMS    0x0C0000u   // float[262144] (1 MB)
#define WS_COUNTS  0x1C0000u   // float[1024]
#define WS_EN      0x1C1000u   // float[1024]
#define WS_SM      0x1C2000u   // float[1024] (fallback only)
#define WS_OFFS    0x1C3000u   // int[1024]
#define WS_CURSOR  0x1C4000u   // int[1024]
#define WS_LOSS    0x1C5000u   // double[1]
#define WS_END_SM  0x1C6000u
// fp16 path regions
#define WS_ESPLIT  0x290000u   // fp16[1024*256] (512 KB), e scaled by 256
#define WS_TOP2    0x390000u   // ulonglong2[65536*4] (4 MB)
#define WS_ZSPLIT  0x1000000u  // fp16[65536*256] (32 MB)
#define WS_END_XL  0x3000000u

#define TAU 2.0e-4f

typedef float f32x4 __attribute__((ext_vector_type(4)));
typedef _Float16 f16x8 __attribute__((ext_vector_type(8)));
typedef unsigned short ushort_t;
typedef unsigned long long u64;

static __device__ inline float fmul_rn_opaque(float a, float b) {
  float r = a * b;
  asm volatile("" : "+v"(r));
  return r;
}

static __device__ inline ushort_t f2h(float x) {   // f32 -> fp16 RNE bits
  _Float16 h = (_Float16)x;
  ushort_t u;
  __builtin_memcpy(&u, &h, 2);
  return u;
}
static __device__ inline float h2f(ushort_t u) {
  _Float16 h;
  __builtin_memcpy(&h, &u, 2);
  return (float)h;
}

static __device__ inline u64 skey(float s, int j) {
  unsigned int u = __float_as_uint(s);
  u = u ^ ((unsigned int)((int)u >> 31) | 0x80000000u);
  return ((u64)u << 32) | (unsigned int)j;
}
static __device__ inline float key_s(u64 k) {
  unsigned int u = (unsigned int)(k >> 32);
  u = (u & 0x80000000u) ? (u ^ 0x80000000u) : ~u;
  return __uint_as_float(u);
}

// async global->LDS, 16B per lane (lds dest = wave-uniform base + lane*16)
static __device__ __forceinline__ void gload16(const void* g, void* l) {
  __builtin_amdgcn_global_load_lds(
      (const __attribute__((address_space(1))) void*)g,
      (__attribute__((address_space(3))) void*)l, 16, 0, 0);
}

// numpy pairwise_sum replica for n=256 (fallback kernels only)
template <typename F>
static __device__ inline float np_pairwise256(F term) {
  float h0 = 0.f, h1 = 0.f;
#pragma unroll
  for (int half = 0; half < 2; ++half) {
    const int base = half * 128;
    float r[8];
#pragma unroll
    for (int k = 0; k < 8; ++k) r[k] = term(base + k);
    for (int i = 8; i < 128; i += 8) {
#pragma unroll
      for (int k = 0; k < 8; ++k) r[k] += term(base + i + k);
    }
    float v = ((r[0] + r[1]) + (r[2] + r[3])) + ((r[4] + r[5]) + (r[6] + r[7]));
    if (half == 0) h0 = v; else h1 = v;
  }
  return h0 + h1;
}

// ---------------- fused en + esplit (fp16, e*256), 8 lanes per code --------
__global__ __launch_bounds__(256) void k_eprep(const float* __restrict__ emb,
                                               float* __restrict__ en,
                                               ushort_t* __restrict__ esplit) {
  const int tid = threadIdx.x;
  const int j = blockIdx.x * 32 + (tid >> 3);   // code
  const int k = tid & 7;
  const float* e = emb + (size_t)j * D_;

  float h[2];
#pragma unroll
  for (int half = 0; half < 2; ++half) {
    float r = 0.f;
    for (int i = 0; i < 16; ++i) {
      float x = e[half * 128 + 8 * i + k];
      float t = fmul_rn_opaque(x, x);
      r = (i == 0) ? t : r + t;
    }
    float s = r + __shfl_xor(r, 1, 64);
    s = s + __shfl_xor(s, 2, 64);
    s = s + __shfl_xor(s, 4, 64);
    h[half] = s;
  }
  if (k == 0) en[j] = h[0] + h[1];

  // esplit: lane k covers d in [k*32, k*32+32); store fp16(256*e)
  ushort_t* er = esplit + (size_t)j * 256;
#pragma unroll
  for (int m = 0; m < 32; m += 4) {
    float4 v = *reinterpret_cast<const float4*>(e + k * 32 + m);
    *reinterpret_cast<ushort4*>(er + k * 32 + m) =
        make_ushort4(f2h(v.x * 256.f), f2h(v.y * 256.f),
                     f2h(v.z * 256.f), f2h(v.w * 256.f));
  }
}

// ---------------- fused zn (np-exact, lane-parallel) + zsplit (fp16) -------
// load side float4-vectorized; store side 2x uint4 per thread.
__global__ __launch_bounds__(256) void k_zprep(const float* __restrict__ z,
                                               float* __restrict__ zn,
                                               ushort_t* __restrict__ zsplit) {
  __shared__ float tile[64][68];
  const int tid = threadIdx.x, bid = blockIdx.x;
  const int tchunk = bid & 31, b = bid >> 5;
  const int n0 = b * T_ + tchunk * 64;
  const int t4 = tid & 15, rq = tid >> 4;   // float4 load mapping
  const int tok = tid >> 2, p = tid & 3;

  float r0 = 0.f, r1 = 0.f, h0 = 0.f;
  for (int c = 0; c < 4; ++c) {
    __syncthreads();   // protect previous chunk's consumers
    const float* zp = z + (size_t)b * D_ * T_ + (size_t)(c * 64) * T_ + tchunk * 64;
#pragma unroll
    for (int i = 0; i < 4; ++i) {
      int dd = rq + 16 * i;
      *reinterpret_cast<float4*>(&tile[dd][t4 * 4]) =
          *reinterpret_cast<const float4*>(&zp[(size_t)dd * T_ + t4 * 4]);
    }
    __syncthreads();
    {
      ushort_t* dst = zsplit + (size_t)(n0 + tok) * 256 + c * 64 + p * 16;
      unsigned int wbuf[8];
#pragma unroll
      for (int jj = 0; jj < 16; jj += 2) {
        float x0 = tile[p * 16 + jj][tok];
        float x1 = tile[p * 16 + jj + 1][tok];
        wbuf[jj >> 1] = (unsigned int)f2h(x0) | ((unsigned int)f2h(x1) << 16);
      }
      *reinterpret_cast<uint4*>(dst) = make_uint4(wbuf[0], wbuf[1], wbuf[2], wbuf[3]);
      *reinterpret_cast<uint4*>(dst + 8) = make_uint4(wbuf[4], wbuf[5], wbuf[6], wbuf[7]);
    }
#pragma unroll
    for (int il = 0; il < 8; ++il) {
      float x0 = tile[8 * il + 2 * p][tok];
      float x1 = tile[8 * il + 2 * p + 1][tok];
      float t0 = fmul_rn_opaque(x0, x0);
      float t1 = fmul_rn_opaque(x1, x1);
      if ((c & 1) == 0 && il == 0) { r0 = t0; r1 = t1; }
      else { r0 += t0; r1 += t1; }
    }
    if (c & 1) {
      float s = r0 + r1;
      s = s + __shfl_xor(s, 1, 64);
      s = s + __shfl_xor(s, 2, 64);
      if (c == 1) h0 = s;
      else if (p == 0) zn[n0 + tok] = h0 + s;
    }
  }
}

// ---------------- top-2 merge helper ----------------
static __device__ inline void top2merge(u64& k1, u64& k2, u64 o1, u64 o2) {
  if (o1 < k1) { u64 t = k1 < o2 ? k1 : o2; k2 = t; k1 = o1; }
  else { k2 = k2 < o1 ? k2 : o1; }
}

// ---------------- MFMA distance GEMM + per-tile top-2 filter ----------------
// OPERAND-SWAPPED: mfma(E, Z) -> C[row=code][col=token]; lane-local top-2,
// 2 shuffle merges + 2-way LDS merge. Screen key s' = fl(en_j - acc*2^-7).
__global__ __launch_bounds__(512) void k_gemm(
    const ushort_t* __restrict__ zsplit, const ushort_t* __restrict__ esplit,
    const float* __restrict__ en, ulonglong2* __restrict__ top2) {
  __shared__ char ldsbuf[65536];   // [Z 32K | E 32K], single buffer

  const int tid = threadIdx.x;
  const int w = blockIdx.x;
  const int xcd = w & 7;
  const int local = w >> 3;                  // 0..63
  const int tt = (xcd << 5) + (local >> 2);  // token tile 0..255
  const int ct = local & 3;                  // code tile 0..3
  const int r0 = tt * 256, c0 = ct * 256;

  const int lane = tid & 63;
  const int wv = tid >> 6;          // wave 0..7
  const int wm = wv >> 2, wn = wv & 3;   // wm: code half, wn: token quarter
  const int m16 = lane & 15;
  const int g = lane >> 4;
  const int gb = g << 4;            // k-group byte offset

  const int rl = lane >> 3;
  const int vlane = rl * 512 + ((((lane & 7) << 4)) ^ (rl << 4));
  const char* gza = (const char*)zsplit + (size_t)(r0 + wv * 32) * 512 + vlane;
  const char* gea = (const char*)esplit + (size_t)(c0 + wv * 32) * 512 + vlane;

  f32x4 acc[8][4];   // [mi: code sub][ni: token sub]
#pragma unroll
  for (int mi = 0; mi < 8; ++mi)
#pragma unroll
    for (int ni = 0; ni < 4; ++ni) acc[mi][ni] = f32x4{0.f, 0.f, 0.f, 0.f};

  auto STAGE = [&](int it_) {
    const int kb = it_ << 7;                      // 64 fp16 = 128 bytes
    char* lz = ldsbuf + wv * 4096;
    char* le = ldsbuf + 32768 + wv * 4096;
    const char* ga = gza + kb;
    const char* ge = gea + kb;
#pragma unroll
    for (int i = 0; i < 4; ++i) {
      gload16(ga + i * 4096, lz + i * 1024);
      gload16(ge + i * 4096, le + i * 1024);
    }
  };

  STAGE(0);
  __builtin_amdgcn_sched_barrier(0);

  const char* Zb = ldsbuf;
  const char* Eb = ldsbuf + 32768;
  for (int it = 0; it < 4; ++it) {
    asm volatile("s_waitcnt vmcnt(0)" ::: "memory");
    __builtin_amdgcn_sched_barrier(0);
    __builtin_amdgcn_s_barrier();          // loads landed for all waves
    __builtin_amdgcn_sched_barrier(0);

#pragma unroll
    for (int ks = 0; ks < 2; ++ks) {
      f16x8 ef[8], zf[4];
#pragma unroll
      for (int mi = 0; mi < 8; ++mi) {     // A-operand: codes
        int row = wm * 128 + mi * 16 + m16;
        ef[mi] = *reinterpret_cast<const f16x8*>(
            Eb + row * 128 + (((ks << 6) + gb) ^ ((row & 7) << 4)));
      }
#pragma unroll
      for (int ni = 0; ni < 4; ++ni) {     // B-operand: tokens
        int row = wn * 64 + ni * 16 + m16;
        zf[ni] = *reinterpret_cast<const f16x8*>(
            Zb + row * 128 + (((ks << 6) + gb) ^ ((row & 7) << 4)));
      }
#pragma unroll
      for (int mi = 0; mi < 8; ++mi)
#pragma unroll
        for (int ni = 0; ni < 4; ++ni)
          acc[mi][ni] = __builtin_amdgcn_mfma_f32_16x16x32_f16(
              ef[mi], zf[ni], acc[mi][ni], 0, 0, 0);
    }
    asm volatile("s_waitcnt lgkmcnt(0)" ::: "memory");
    __builtin_amdgcn_sched_barrier(0);
    __builtin_amdgcn_s_barrier();          // all reads done before overwrite
    __builtin_amdgcn_sched_barrier(0);
    if (it < 3) STAGE(it + 1);
    __builtin_amdgcn_sched_barrier(0);
  }

  // epilogue: lane-local top-2 (32 codes/lane)
  u64* pairbuf = (u64*)ldsbuf;   // [256 tok][2 wm][2], 8 KB, aliases staging
  float env[8][4];
#pragma unroll
  for (int mi = 0; mi < 8; ++mi)
#pragma unroll
    for (int rg = 0; rg < 4; ++rg)
      env[mi][rg] = en[c0 + wm * 128 + mi * 16 + g * 4 + rg];

#pragma unroll
  for (int ni = 0; ni < 4; ++ni) {
    const int tok = wn * 64 + ni * 16 + m16;
    u64 k1 = ~0ull, k2 = ~0ull;
#pragma unroll
    for (int mi = 0; mi < 8; ++mi) {
#pragma unroll
      for (int rg = 0; rg < 4; ++rg) {
        int j = c0 + wm * 128 + mi * 16 + g * 4 + rg;
        float s = env[mi][rg] - acc[mi][ni][rg] * 0.0078125f;  // exact scale
        u64 key = skey(s, j);
        if (key < k1) { k2 = k1; k1 = key; }
        else if (key < k2) { k2 = key; }
      }
    }
    u64 o1 = (u64)__shfl_xor((long long)k1, 16, 64);
    u64 o2 = (u64)__shfl_xor((long long)k2, 16, 64);
    top2merge(k1, k2, o1, o2);
    o1 = (u64)__shfl_xor((long long)k1, 32, 64);
    o2 = (u64)__shfl_xor((long long)k2, 32, 64);
    top2merge(k1, k2, o1, o2);
    if (g == 0) {
      pairbuf[(tok * 2 + wm) * 2 + 0] = k1;
      pairbuf[(tok * 2 + wm) * 2 + 1] = k2;
    }
  }
  __syncthreads();
  if (tid < 256) {
    u64 a1 = pairbuf[(tid * 2 + 0) * 2 + 0], a2 = pairbuf[(tid * 2 + 0) * 2 + 1];
    top2merge(a1, a2, pairbuf[(tid * 2 + 1) * 2 + 0], pairbuf[(tid * 2 + 1) * 2 + 1]);
    top2[(size_t)(r0 + tid) * 4 + ct] = make_ulonglong2(a1, a2);
  }
}

// ---------------- merge top-2; exact rescreen; loss from winning key ------
__global__ __launch_bounds__(256) void k_merge(
    const ulonglong2* __restrict__ top2, const float* __restrict__ z,
    const float* __restrict__ emb, const float* __restrict__ en,
    const float* __restrict__ zn, int* __restrict__ ids,
    float* __restrict__ counts, double* __restrict__ loss,
    float* __restrict__ out) {
  int n = blockIdx.x * 256 + threadIdx.x;
  const ulonglong2* tp = top2 + (size_t)n * 4;
  const float znv = zn[n];
  u64 k[8];
#pragma unroll
  for (int i = 0; i < 4; ++i) {
    ulonglong2 v = tp[i];
    k[2 * i] = v.x; k[2 * i + 1] = v.y;
  }
  u64 mn = k[0];
#pragma unroll
  for (int i = 1; i < 8; ++i) mn = k[i] < mn ? k[i] : mn;
  float lim = key_s(mn) + TAU;
  int cnt = 0;
  int cj[4] = {0, 0, 0, 0};
#pragma unroll
  for (int i = 0; i < 8; ++i) {
    if (key_s(k[i]) <= lim) {
      if (cnt < 4) cj[cnt] = (int)(k[i] & 1023u);
      cnt++;
    }
  }
  int jf;
  float loss_n;   // ||z_n - e_jf||^2
  if (cnt == 1) {
    jf = (int)(mn & 1023u);
    loss_n = znv + key_s(mn);   // gemm keys: s' = en - 2G
  } else {
    int b = n >> 11, t = n & 2047;
    const float* zb = z + (size_t)b * (D_ * (size_t)T_) + t;
    const float* e0 = emb + (size_t)cj[0] * D_;
    const float* e1 = emb + (size_t)cj[1] * D_;
    const float* e2 = emb + (size_t)cj[2] * D_;
    const float* e3 = emb + (size_t)cj[3] * D_;
    float a0 = 0.f, a1 = 0.f, a2 = 0.f, a3 = 0.f;
    for (int d = 0; d < D_; ++d) {   // ascending d, single acc: np-faithful
      float zv = zb[(size_t)d * T_];
      a0 = fmaf(zv, e0[d], a0);
      a1 = fmaf(zv, e1[d], a1);
      a2 = fmaf(zv, e2[d], a2);
      a3 = fmaf(zv, e3[d], a3);
    }
    float av[4] = {a0, a1, a2, a3};
    u64 best = ~0ull;
#pragma unroll
    for (int c = 0; c < 4; ++c) {
      if (c < cnt) {
        float A = znv + en[cj[c]];
        float s = A - 2.0f * av[c];
        u64 key = skey(s, cj[c]);
        best = key < best ? key : best;
      }
    }
    jf = (int)(best & 1023u);
    loss_n = key_s(best);       // rescreen keys include zn
  }
  ids[n] = jf;
  out[OFF_IDS + (unsigned)n] = (float)jf;
  unsafeAtomicAdd(&counts[jf], 1.0f);

  // block-reduce loss
  float acc = loss_n;
#pragma unroll
  for (int o = 32; o; o >>= 1) acc += __shfl_down(acc, o);
  __shared__ float ls[4];
  int tid = threadIdx.x;
  if ((tid & 63) == 0) ls[tid >> 6] = acc;
  __syncthreads();
  if (tid == 0)
    unsafeAtomicAdd(loss, (double)(ls[0] + ls[1] + ls[2] + ls[3]));
}

// ---------------- exclusive scan of counts -> offs, cursor ----------------
__global__ __launch_bounds__(1024) void k_offsets(const float* __restrict__ counts,
                                                  int* __restrict__ offs,
                                                  int* __restrict__ cursor) {
  int k = threadIdx.x;
  int c = (int)counts[k];
  __shared__ int s[1024];
  s[k] = c;
  __syncthreads();
  for (int off = 1; off < 1024; off <<= 1) {
    int v = (k >= off) ? s[k - off] : 0;
    __syncthreads();
    s[k] += v;
    __syncthreads();
  }
  int excl = s[k] - c;
  offs[k] = excl;
  cursor[k] = excl;
}

// ---------------- inverted index: order[slot] = (id<<16)|token -----------
__global__ __launch_bounds__(256) void k_bucket(const int* __restrict__ ids,
                                                int* __restrict__ cursor,
                                                int* __restrict__ order) {
  int n = blockIdx.x * 256 + threadIdx.x;
  int id = ids[n] & 1023;
  int slot = atomicAdd(&cursor[id], 1);
  order[slot & (N_ - 1)] = (id << 16) | n;
}

// ---------------- segment sums from fp16 zsplit (d-pair uint loads) -------
__global__ __launch_bounds__(256) void k_sums_bf(const ushort_t* __restrict__ zsplit,
                                                 const int* __restrict__ order,
                                                 float* __restrict__ sums) {
  __shared__ int pk[128];
  const int tid = threadIdx.x;
  if (tid < 128) pk[tid] = order[blockIdx.x * 128 + tid];
  __syncthreads();
  const int half = tid >> 7;
  const int l = tid & 127;
  const int s0 = half * 64;
  float a0 = 0.f, a1 = 0.f;
  int cur = pk[s0] >> 16;
#pragma unroll 4
  for (int i = 0; i < 64; ++i) {
    int v = pk[s0 + i];
    int code = v >> 16;
    if (code != cur) {
      unsafeAtomicAdd(&sums[(size_t)cur * D_ + 2 * l], a0);
      unsafeAtomicAdd(&sums[(size_t)cur * D_ + 2 * l + 1], a1);
      a0 = 0.f; a1 = 0.f; cur = code;
    }
    const char* row = (const char*)zsplit + (size_t)(v & 0xFFFF) * 512;
    unsigned int hw = *reinterpret_cast<const unsigned int*>(row + 4 * l);
    a0 += h2f((ushort_t)(hw & 0xFFFF));
    a1 += h2f((ushort_t)(hw >> 16));
  }
  unsafeAtomicAdd(&sums[(size_t)cur * D_ + 2 * l], a0);
  unsafeAtomicAdd(&sums[(size_t)cur * D_ + 2 * l + 1], a1);
}

// ---------------- z_q write (gather-only; loss comes from k_merge) --------
__global__ __launch_bounds__(256) void k_zq(
    const float* __restrict__ emb, const int* __restrict__ ids,
    float* __restrict__ out) {
  __shared__ float tile[64][68];
  const int tid = threadIdx.x;
  const int bid = blockIdx.x;
  const int tchunk = bid & 31;
  const int dchunk = (bid >> 5) & 3;
  const int b = bid >> 7;
  const int n0 = b * T_ + tchunk * 64;
  {
    int tok = tid >> 2, part = tid & 3;
    int id = ids[n0 + tok] & 1023;
    const float* er = emb + (size_t)id * D_ + dchunk * 64 + part * 16;
#pragma unroll
    for (int k = 0; k < 4; ++k) {
      float4 v = *reinterpret_cast<const float4*>(er + 4 * k);
      int d = part * 16 + 4 * k;
      tile[d + 0][tok] = v.x; tile[d + 1][tok] = v.y;
      tile[d + 2][tok] = v.z; tile[d + 3][tok] = v.w;
    }
  }
  __syncthreads();
  const int t4 = tid & 15, dq = tid >> 4;
  const size_t zbase = (size_t)b * D_ * T_ + (size_t)(dchunk * 64) * T_ + tchunk * 64;
#pragma unroll
  for (int i = 0; i < 4; ++i) {
    int dd = dq + 16 * i;
    size_t a = zbase + (size_t)dd * T_ + t4 * 4;
    *reinterpret_cast<float4*>(out + OFF_ZQ + a) =
        *reinterpret_cast<const float4*>(&tile[dd][t4 * 4]);
  }
}

// ---------------- fused: counts/n/sm + weight + embedding + loss out ------
__global__ __launch_bounds__(256) void k_weight(
    const float* __restrict__ ema_count, const float* __restrict__ counts,
    const float* __restrict__ ema_weight, const float* __restrict__ sums,
    const double* __restrict__ loss, float* __restrict__ out) {
  const int k = blockIdx.x;
  const int tid = threadIdx.x;
  __shared__ float red[4];

  float part = 0.f;
#pragma unroll
  for (int i = 0; i < 4; ++i) {
    int idx = tid + 256 * i;
    part += 0.99f * ema_count[idx] + 0.01f * counts[idx];
  }
#pragma unroll
  for (int o = 32; o; o >>= 1) part += __shfl_down(part, o);
  if ((tid & 63) == 0) red[tid >> 6] = part;
  __syncthreads();
  float n = red[0] + red[1] + red[2] + red[3];

  float nck = 0.99f * ema_count[k] + 0.01f * counts[k];
  float smo = (nck + 1.0e-5f) / (n + 1024.0f * 1.0e-5f) * n;

  int i = k * 256 + tid;
  float w = 0.99f * ema_weight[i] + 0.01f * sums[i];
  out[OFF_W + i] = w;
  out[OFF_EMB + i] = w / smo;
  if (tid == 0) {
    out[OFF_CNT + k] = nck;
    if (k == 0) {
      double mean = loss[0] / 16777216.0;
      out[OFF_LOSS] = (float)(1.25 * mean);
    }
  }
}

// ======================= fallback kernels ========================
__global__ __launch_bounds__(256) void k_en(const float* __restrict__ emb,
                                            float* __restrict__ en) {
  int j = blockIdx.x * 256 + threadIdx.x;
  const float* e = emb + (size_t)j * D_;
  en[j] = np_pairwise256([&](int d) { float x = e[d]; return fmul_rn_opaque(x, x); });
}

__global__ __launch_bounds__(256) void k_zn(const float* __restrict__ z,
                                            float* __restrict__ zn) {
  int n = blockIdx.x * 256 + threadIdx.x;
  int b = n >> 11, t = n & 2047;
  const float* zp = z + (size_t)b * (D_ * (size_t)T_) + t;
  zn[n] = np_pairwise256([&](int d) {
    float x = zp[(size_t)d * T_];
    return fmul_rn_opaque(x, x);
  });
}

__global__ __launch_bounds__(256) void k_assign(
    const float* __restrict__ z, const float* __restrict__ emb,
    const float* __restrict__ en, const float* __restrict__ zn,
    int* __restrict__ ids, float* __restrict__ counts,
    float* __restrict__ out) {
  __shared__ float zs[16][128];
  __shared__ float es[16][128];
  const int tid = threadIdx.x;
  const int tx = tid & 31;
  const int ty = tid >> 5;
  const int r0 = blockIdx.x * 128;
  const int b  = r0 >> 11;
  const int t0 = r0 & 2047;
  const float* zb = z + (size_t)b * (D_ * (size_t)T_) + t0;
  u64 keys[16];
#pragma unroll
  for (int r = 0; r < 16; ++r) keys[r] = ~0ull;
  for (int jc = 0; jc < K_; jc += 128) {
    float acc[16][4];
#pragma unroll
    for (int r = 0; r < 16; ++r)
#pragma unroll
      for (int c = 0; c < 4; ++c) acc[r][c] = 0.f;
    for (int d0 = 0; d0 < D_; d0 += 16) {
      __syncthreads();
#pragma unroll
      for (int i = 0; i < 2; ++i) {
        int slot = tid + 256 * i;
        int dd = slot >> 5, t4 = slot & 31;
        *reinterpret_cast<float4*>(&zs[dd][t4 * 4]) =
            *reinterpret_cast<const float4*>(&zb[(size_t)(d0 + dd) * T_ + t4 * 4]);
      }
#pragma unroll
      for (int i = 0; i < 2; ++i) {
        int slot = tid + 256 * i;
        int c = slot & 127, g = slot >> 7;
        int dd0 = g * 4;
        float4 ev = *reinterpret_cast<const float4*>(
            &emb[(size_t)(jc + c) * D_ + d0 + dd0]);
        es[dd0 + 0][c] = ev.x; es[dd0 + 1][c] = ev.y;
        es[dd0 + 2][c] = ev.z; es[dd0 + 3][c] = ev.w;
      }
      __syncthreads();
#pragma unroll
      for (int dd = 0; dd < 16; ++dd) {
        float4 e4 = *reinterpret_cast<const float4*>(&es[dd][tx * 4]);
        float4 z0 = *reinterpret_cast<const float4*>(&zs[dd][ty * 16]);
        float4 z1 = *reinterpret_cast<const float4*>(&zs[dd][ty * 16 + 4]);
        float4 z2 = *reinterpret_cast<const float4*>(&zs[dd][ty * 16 + 8]);
        float4 z3 = *reinterpret_cast<const float4*>(&zs[dd][ty * 16 + 12]);
        float zr[16] = {z0.x, z0.y, z0.z, z0.w, z1.x, z1.y, z1.z, z1.w,
                        z2.x, z2.y, z2.z, z2.w, z3.x, z3.y, z3.z, z3.w};
        float ec[4] = {e4.x, e4.y, e4.z, e4.w};
#pragma unroll
        for (int r = 0; r < 16; ++r)
#pragma unroll
          for (int c = 0; c < 4; ++c) acc[r][c] += zr[r] * ec[c];
      }
    }
#pragma unroll
    for (int r = 0; r < 16; ++r) {
      float znp = zn[r0 + ty * 16 + r];
      u64 kk = keys[r];
#pragma unroll
      for (int c = 0; c < 4; ++c) {
        int j = jc + tx * 4 + c;
        float A = znp + en[j];
        float s = A - 2.0f * acc[r][c];
        u64 key = skey(s, j);
        kk = key < kk ? key : kk;
      }
      keys[r] = kk;
    }
  }
#pragma unroll
  for (int r = 0; r < 16; ++r) {
    u64 kk = keys[r];
#pragma unroll
    for (int m = 1; m < 32; m <<= 1) {
      u64 o = (u64)__shfl_xor((long long)kk, m, 32);
      kk = o < kk ? o : kk;
    }
    keys[r] = kk;
  }
  if ((tid & 31) == 0) {
#pragma unroll
    for (int r = 0; r < 16; ++r) {
      int n = r0 + ty * 16 + r;
      int jf = (int)(keys[r] & 1023u);
      ids[n] = jf;
      out[OFF_IDS + (unsigned)n] = (float)jf;
      unsafeAtomicAdd(&counts[jf], 1.0f);
    }
  }
}

__global__ __launch_bounds__(256) void k_scatter_atomic(
    const float* __restrict__ z, const float* __restrict__ emb,
    const int* __restrict__ ids, float* __restrict__ sums,
    double* __restrict__ loss, float* __restrict__ out) {
  const int tid = threadIdx.x;
  unsigned int gi = blockIdx.x * 256u + (unsigned int)tid;
  int t4 = (int)(gi & 511u);
  int bd = (int)(gi >> 9);
  int d  = bd & 255;
  int b  = bd >> 8;
  size_t base = (size_t)bd * T_ + (size_t)t4 * 4;
  const float4 zv = *reinterpret_cast<const float4*>(z + base);
  const int tb = b * T_ + t4 * 4;
  float zz[4] = {zv.x, zv.y, zv.z, zv.w};
  float e4[4];
  float acc = 0.f;
#pragma unroll
  for (int u = 0; u < 4; ++u) {
    int id = ids[tb + u] & 1023;
    float e = emb[(size_t)id * D_ + d];
    float df = zz[u] - e;
    acc += df * df;
    e4[u] = e;
    unsafeAtomicAdd(&sums[(size_t)id * D_ + d], zz[u]);
  }
  *reinterpret_cast<float4*>(out + OFF_ZQ + base) =
      make_float4(e4[0], e4[1], e4[2], e4[3]);
#pragma unroll
  for (int o = 32; o; o >>= 1) acc += __shfl_down(acc, o);
  __shared__ float ls[4];
  int lane = tid & 63, wid = tid >> 6;
  if (lane == 0) ls[wid] = acc;
  __syncthreads();
  if (tid == 0) unsafeAtomicAdd(loss, (double)(ls[0] + ls[1] + ls[2] + ls[3]));
}

__global__ __launch_bounds__(1024) void k_count_fb(
    const float* __restrict__ ema_count, const float* __restrict__ counts,
    float* __restrict__ sm, const double* __restrict__ loss,
    float* __restrict__ out) {
  int k = threadIdx.x;
  float nc = 0.99f * ema_count[k] + 0.01f * counts[k];
  __shared__ float red[1024];
  red[k] = nc;
  __syncthreads();
  for (int s = 512; s > 0; s >>= 1) {
    if (k < s) red[k] += red[k + s];
    __syncthreads();
  }
  float n = red[0];
  float smo = (nc + 1.0e-5f) / (n + 1024.0f * 1.0e-5f) * n;
  sm[k] = smo;
  out[OFF_CNT + k] = nc;
  if (k == 0) {
    double mean = loss[0] / 16777216.0;
    out[OFF_LOSS] = (float)(1.25 * mean);
  }
}

__global__ __launch_bounds__(256) void k_weight_fb(
    const float* __restrict__ ema_weight, const float* __restrict__ sums,
    const float* __restrict__ sm, float* __restrict__ out) {
  int i = blockIdx.x * 256 + threadIdx.x;
  int k = i >> 8;
  float w = 0.99f * ema_weight[i] + 0.01f * sums[i];
  out[OFF_W + i] = w;
  out[OFF_EMB + i] = w / sm[k];
}

// ============================== launcher =================================
extern "C" void kernel_launch(void* const* d_in, const int* in_sizes, int n_in,
                              void* d_out, int out_size, void* d_ws, size_t ws_size,
                              hipStream_t stream) {
  const float* z          = (const float*)d_in[0];
  const float* emb        = (const float*)d_in[1];
  const float* ema_count  = (const float*)d_in[2];
  const float* ema_weight = (const float*)d_in[3];
  float* out = (float*)d_out;
  char* ws = (char*)d_ws;
  if (ws_size < (size_t)WS_END_SM) return;

  int*    ids    = (int*)(ws + WS_IDS);
  float*  zn     = (float*)(ws + WS_ZN);
  int*    order  = (int*)(ws + WS_ORDER);
  float*  sums   = (float*)(ws + WS_SUMS);
  float*  counts = (float*)(ws + WS_COUNTS);
  float*  en     = (float*)(ws + WS_EN);
  float*  sm     = (float*)(ws + WS_SM);
  int*    offs   = (int*)(ws + WS_OFFS);
  int*    cursor = (int*)(ws + WS_CURSOR);
  double* loss   = (double*)(ws + WS_LOSS);

  hipMemsetAsync(ws + WS_SUMS, 0, WS_END_SM - WS_SUMS, stream);

  if (ws_size >= (size_t)WS_END_XL) {
    // -------- fp16 MFMA path --------
    ushort_t*   esplit = (ushort_t*)(ws + WS_ESPLIT);
    ushort_t*   zsplit = (ushort_t*)(ws + WS_ZSPLIT);
    ulonglong2* top2   = (ulonglong2*)(ws + WS_TOP2);

    k_eprep  <<<K_ / 32, 256, 0, stream>>>(emb, en, esplit);
    k_zprep  <<<B_ * (T_ / 64), 256, 0, stream>>>(z, zn, zsplit);
    k_gemm   <<<(K_ / 256) * (N_ / 256), 512, 0, stream>>>(zsplit, esplit, en, top2);
    k_merge  <<<N_ / 256, 256, 0, stream>>>(top2, z, emb, en, zn, ids, counts, loss, out);
    k_offsets<<<1, 1024, 0, stream>>>(counts, offs, cursor);
    k_bucket <<<N_ / 256, 256, 0, stream>>>(ids, cursor, order);
    k_sums_bf<<<N_ / 128, 256, 0, stream>>>(zsplit, order, sums);
    k_zq     <<<B_ * (D_ / 64) * (T_ / 64), 256, 0, stream>>>(emb, ids, out);
    k_weight <<<K_, 256, 0, stream>>>(ema_count, counts, ema_weight, sums, loss, out);
  } else {
    // -------- fallback: fp32 VALU assign + atomic scatter --------
    k_en <<<K_ / 256, 256, 0, stream>>>(emb, en);
    k_zn <<<N_ / 256, 256, 0, stream>>>(z, zn);
    k_assign<<<N_ / 128, 256, 0, stream>>>(z, emb, en, zn, ids, counts, out);
    k_scatter_atomic<<<(N_ * (D_ / 4)) / 256, 256, 0, stream>>>(z, emb, ids, sums, loss, out);
    k_count_fb <<<1, 1024, 0, stream>>>(ema_count, counts, sm, loss, out);
    k_weight_fb<<<(K_ * D_) / 256, 256, 0, stream>>>(ema_weight, sums, sm, out);
  }
}